// Round 2
// baseline (1185.822 us; speedup 1.0000x reference)
//
#include <hip/hip_runtime.h>
#include <math.h>

// ---------- constants ----------
#define CDIM 192
#define HIDD 768

typedef float f32x4 __attribute__((ext_vector_type(4)));
typedef short bf16x8 __attribute__((ext_vector_type(8)));

__device__ __forceinline__ short f2bf(float f) {
  unsigned u = __builtin_bit_cast(unsigned, f);
  u = (u + 0x7FFFu + ((u >> 16) & 1u)) >> 16;
  return (short)u;
}
__device__ __forceinline__ float bf2f(short s) {
  unsigned u = ((unsigned)(unsigned short)s) << 16;
  return __builtin_bit_cast(float, u);
}
__device__ __forceinline__ float gelu_exact(float x) {
  return 0.5f * x * (1.0f + erff(x * 0.70710678118654752f));
}

// ---------- LayerNorm (fp32 in -> bf16 out), 4 rows/block ----------
__global__ __launch_bounds__(256) void ln_kernel(const float* __restrict__ x,
                                                 const float* __restrict__ w,
                                                 const float* __restrict__ b,
                                                 short* __restrict__ out) {
  int lane = threadIdx.x & 63;
  long row = (long)blockIdx.x * 4 + (threadIdx.x >> 6);
  const float* xr = x + row * CDIM;
  float v0 = xr[lane], v1 = xr[lane + 64], v2 = xr[lane + 128];
  float s = v0 + v1 + v2;
  float s2 = v0 * v0 + v1 * v1 + v2 * v2;
#pragma unroll
  for (int m = 1; m < 64; m <<= 1) {
    s += __shfl_xor(s, m);
    s2 += __shfl_xor(s2, m);
  }
  float mu = s * (1.0f / 192.0f);
  float rstd = rsqrtf(s2 * (1.0f / 192.0f) - mu * mu + 1e-5f);
  short* o = out + row * CDIM;
  o[lane] = f2bf((v0 - mu) * rstd * w[lane] + b[lane]);
  o[lane + 64] = f2bf((v1 - mu) * rstd * w[lane + 64] + b[lane + 64]);
  o[lane + 128] = f2bf((v2 - mu) * rstd * w[lane + 128] + b[lane + 128]);
}

// ---------- weight prep: W[K][N] fp32 -> Bt[N][K] bf16 ----------
__global__ __launch_bounds__(256) void wprep_kernel(const float* __restrict__ w,
                                                    short* __restrict__ bt,
                                                    int K, int N) {
  long i = (long)blockIdx.x * 256 + threadIdx.x;  // over N*K, bt-linear
  if (i >= (long)K * N) return;
  int n = (int)(i / K), k = (int)(i % K);
  bt[i] = f2bf(w[(long)k * N + n]);
}

// ---------- generic GEMM: out[M][NTOT] = A[M][KTOT](bf16) @ W + epilogue ----------
// EPI 0: + bias(B0 cols<192 / B1 cols>=192) -> bf16   (qkv)
// EPI 1: + bias + resid(fp32)               -> fp32   (proj / l2)
// EPI 2: gelu(+ bias)                       -> bf16   (l1)
template <int KTOT, int NTOT, int EPI>
__global__ __launch_bounds__(256) void gemm_kernel(
    const short* __restrict__ A, const short* __restrict__ Bt,
    const float* __restrict__ B0, const float* __restrict__ B1,
    const float* __restrict__ resid, void* __restrict__ outp, int iters) {
  constexpr int KCH = KTOT / 192;
  __shared__ short As[128][200];  // row stride 400B = 16*25 -> aligned, low-conflict
  const int tid = threadIdx.x;
  const int lane = tid & 63;
  const int wid = tid >> 6;
  const int lr = lane & 15;
  const int lg = lane >> 4;
  const int n0 = blockIdx.x * 64;

  bf16x8 bf[6][4];
  auto loadB = [&](int kc) {
#pragma unroll
    for (int ks = 0; ks < 6; ++ks)
#pragma unroll
      for (int ni = 0; ni < 4; ++ni)
        bf[ks][ni] = *(const bf16x8*)(Bt + (long)(n0 + ni * 16 + lr) * KTOT +
                                      kc * 192 + ks * 32 + lg * 8);
  };
  if constexpr (KCH == 1) loadB(0);

  for (int it = 0; it < iters; ++it) {
    long m0 = ((long)blockIdx.y * iters + it) * 128;
    f32x4 acc[2][4] = {};
    for (int kc = 0; kc < KCH; ++kc) {
      if constexpr (KCH > 1) loadB(kc);
      __syncthreads();
#pragma unroll
      for (int p = 0; p < 12; ++p) {
        int ci = tid + p * 256;
        int r = ci / 24, c = ci % 24;
        const float4* src =
            (const float4*)(A + (m0 + r) * KTOT + kc * 192 + c * 8);
        *(float4*)(&As[r][c * 8]) = *src;
      }
      __syncthreads();
#pragma unroll
      for (int ks = 0; ks < 6; ++ks) {
        bf16x8 a0 = *(const bf16x8*)(&As[wid * 32 + lr][ks * 32 + lg * 8]);
        bf16x8 a1 = *(const bf16x8*)(&As[wid * 32 + 16 + lr][ks * 32 + lg * 8]);
#pragma unroll
        for (int ni = 0; ni < 4; ++ni) {
          acc[0][ni] = __builtin_amdgcn_mfma_f32_16x16x32_bf16(a0, bf[ks][ni],
                                                               acc[0][ni], 0, 0, 0);
          acc[1][ni] = __builtin_amdgcn_mfma_f32_16x16x32_bf16(a1, bf[ks][ni],
                                                               acc[1][ni], 0, 0, 0);
        }
      }
    }
    // epilogue: C layout col=lane&15, row=(lane>>4)*4+reg (verified mapping)
#pragma unroll
    for (int mi = 0; mi < 2; ++mi) {
#pragma unroll
      for (int ni = 0; ni < 4; ++ni) {
        int n = n0 + ni * 16 + lr;
        long rowb = m0 + wid * 32 + mi * 16 + lg * 4;
#pragma unroll
        for (int r = 0; r < 4; ++r) {
          float v = acc[mi][ni][r];
          long idx = (rowb + r) * NTOT + n;
          if constexpr (EPI == 0) {
            float bb = (n < 192) ? B0[n] : B1[n - 192];
            ((short*)outp)[idx] = f2bf(v + bb);
          } else if constexpr (EPI == 1) {
            ((float*)outp)[idx] = v + B0[n] + resid[idx];
          } else {
            ((short*)outp)[idx] = f2bf(gelu_exact(v + B0[n]));
          }
        }
      }
    }
  }
}

// ---------- windowed attention: one wave per (batch, window, head) ----------
__global__ __launch_bounds__(64) void attn_kernel(const short* __restrict__ qkv,
                                                  const float* __restrict__ rpb,
                                                  short* __restrict__ y) {
  __shared__ short vT[32][72];  // [d][token]
  __shared__ short P[64][72];   // [q][k]
  const int lane = threadIdx.x;
  const int bid = blockIdx.x;
  const int h = bid % 6;
  const int w = (bid / 6) & 1023;
  const int b = bid / 6144;
  const int wr = w >> 5, wc = w & 31;
  const int lr = lane & 15, lg = lane >> 4;

  auto trow = [&](int t) -> long {  // token in (rolled) window -> original row
    int hr = wr * 8 + (t >> 3);
    int hc = wc * 8 + (t & 7);
    int ho = (hr + 4) & 255;
    int wo = (hc + 4) & 255;
    return (long)b * 65536 + ho * 256 + wo;
  };

  bf16x8 aq[4], bk[4];
#pragma unroll
  for (int i = 0; i < 4; ++i) {
    long rq = trow(i * 16 + lr);
    aq[i] = *(const bf16x8*)(qkv + rq * 576 + h * 32 + lg * 8);
    bk[i] = *(const bf16x8*)(qkv + rq * 576 + 192 + h * 32 + lg * 8);
  }
  {  // stage V transposed: vT[d][token]
    long rv = trow(lane);
    const short* vp = qkv + rv * 576 + 384 + h * 32;
#pragma unroll
    for (int q4 = 0; q4 < 4; ++q4) {
      bf16x8 vv = *(const bf16x8*)(vp + q4 * 8);
#pragma unroll
      for (int j = 0; j < 8; ++j) vT[q4 * 8 + j][lane] = vv[j];
    }
  }

  // S = Q @ K^T (head dim 32 = one K=32 MFMA)
  f32x4 s[4][4] = {};
#pragma unroll
  for (int mi = 0; mi < 4; ++mi)
#pragma unroll
    for (int ni = 0; ni < 4; ++ni)
      s[mi][ni] = __builtin_amdgcn_mfma_f32_16x16x32_bf16(aq[mi], bk[ni],
                                                          s[mi][ni], 0, 0, 0);

  const float SCALE = 0.17677669529663687f;
  float rinv[4][4];
#pragma unroll
  for (int mi = 0; mi < 4; ++mi) {
#pragma unroll
    for (int r = 0; r < 4; ++r) {
      int q = mi * 16 + lg * 4 + r;
      int qh = wr * 8 + (q >> 3), qw = wc * 8 + (q & 7);
      int ridq = 3 * ((qh < 248) ? 0 : ((qh < 252) ? 1 : 2)) +
                 ((qw < 248) ? 0 : ((qw < 252) ? 1 : 2));
      float lv[4];
      float mx = -1e30f;
#pragma unroll
      for (int ni = 0; ni < 4; ++ni) {
        int k = ni * 16 + lr;
        int dr = (q >> 3) - (k >> 3) + 7;
        int dc = (q & 7) - (k & 7) + 7;
        float bias = rpb[(dr * 15 + dc) * 6 + h];
        int kh = wr * 8 + (k >> 3), kw = wc * 8 + (k & 7);
        int ridk = 3 * ((kh < 248) ? 0 : ((kh < 252) ? 1 : 2)) +
                   ((kw < 248) ? 0 : ((kw < 252) ? 1 : 2));
        float lvv = s[mi][ni][r] * SCALE + bias + ((ridq != ridk) ? -100.0f : 0.0f);
        lv[ni] = lvv;
        mx = fmaxf(mx, lvv);
      }
#pragma unroll
      for (int m = 1; m < 16; m <<= 1) mx = fmaxf(mx, __shfl_xor(mx, m));
      float sum = 0.0f;
#pragma unroll
      for (int ni = 0; ni < 4; ++ni) {
        float p = expf(lv[ni] - mx);
        lv[ni] = p;
        sum += p;
      }
#pragma unroll
      for (int m = 1; m < 16; m <<= 1) sum += __shfl_xor(sum, m);
      rinv[mi][r] = 1.0f / sum;
#pragma unroll
      for (int ni = 0; ni < 4; ++ni) P[q][ni * 16 + lr] = f2bf(lv[ni]);
    }
  }
  __syncthreads();

  // O = P @ V (K=64 -> 2 steps)
  f32x4 o[4][2] = {};
#pragma unroll
  for (int ks = 0; ks < 2; ++ks) {
    bf16x8 ap[4], bv[2];
#pragma unroll
    for (int mi = 0; mi < 4; ++mi)
      ap[mi] = *(const bf16x8*)(&P[mi * 16 + lr][ks * 32 + lg * 8]);
#pragma unroll
    for (int ni = 0; ni < 2; ++ni)
      bv[ni] = *(const bf16x8*)(&vT[ni * 16 + lr][ks * 32 + lg * 8]);
#pragma unroll
    for (int mi = 0; mi < 4; ++mi)
#pragma unroll
      for (int ni = 0; ni < 2; ++ni)
        o[mi][ni] = __builtin_amdgcn_mfma_f32_16x16x32_bf16(ap[mi], bv[ni],
                                                            o[mi][ni], 0, 0, 0);
  }
#pragma unroll
  for (int mi = 0; mi < 4; ++mi) {
#pragma unroll
    for (int r = 0; r < 4; ++r) {
      int q = mi * 16 + lg * 4 + r;
      long rq = trow(q);
      float ri = rinv[mi][r];
#pragma unroll
      for (int ni = 0; ni < 2; ++ni)
        y[rq * 192 + h * 32 + ni * 16 + lr] = f2bf(o[mi][ni][r] * ri);
    }
  }
}

// ---------- depthwise 3x3 conv + GELU on one 128-row chunk ----------
// hbc: [130 slots][256][768] bf16, slot j = global y (yh*128 - 1 + j)
// h2c: [128][256][768] bf16, rows y = yh*128 + py
__global__ __launch_bounds__(256) void dwconv_kernel(const short* __restrict__ hbc,
                                                     const float* __restrict__ dww,
                                                     const float* __restrict__ dwb,
                                                     short* __restrict__ h2c,
                                                     int yh) {
  long t = (long)blockIdx.x * 256 + threadIdx.x;  // 128*256*96 = 3,145,728
  int cg = (int)(t % 96);
  int px = (int)((t / 96) % 256);
  int py = (int)(t / 24576);  // 0..127
  int ybase = yh * 128 + py;
  float acc[8] = {0, 0, 0, 0, 0, 0, 0, 0};
#pragma unroll
  for (int dy = 0; dy < 3; ++dy) {
    int yy = ybase + dy - 1;
    if (yy < 0 || yy > 255) continue;
    int slot = py + dy;  // yy - (yh*128 - 1)
#pragma unroll
    for (int dx = 0; dx < 3; ++dx) {
      int xx = px + dx - 1;
      if (xx < 0 || xx > 255) continue;
      long base = ((long)slot * 256 + xx) * 768 + cg * 8;
      bf16x8 hv = *(const bf16x8*)(hbc + base);
#pragma unroll
      for (int j = 0; j < 8; ++j)
        acc[j] += bf2f(hv[j]) * dww[(dy * 3 + dx) * 768 + cg * 8 + j];
    }
  }
  bf16x8 ov;
#pragma unroll
  for (int j = 0; j < 8; ++j) ov[j] = f2bf(gelu_exact(acc[j] + dwb[cg * 8 + j]));
  *(bf16x8*)(h2c + t * 8) = ov;
}

// ---------- launch ----------
extern "C" void kernel_launch(void* const* d_in, const int* in_sizes, int n_in,
                              void* d_out, int out_size, void* d_ws, size_t ws_size,
                              hipStream_t stream) {
  const float* x = (const float*)d_in[0];
  const float* n1w = (const float*)d_in[1];
  const float* n1b = (const float*)d_in[2];
  const float* q_w = (const float*)d_in[3];
  const float* q_b = (const float*)d_in[4];
  const float* kv_w = (const float*)d_in[5];
  const float* kv_b = (const float*)d_in[6];
  const float* rpb = (const float*)d_in[7];
  const float* proj_w = (const float*)d_in[8];
  const float* proj_b = (const float*)d_in[9];
  const float* n2w = (const float*)d_in[10];
  const float* n2b = (const float*)d_in[11];
  const float* l1_w = (const float*)d_in[12];
  const float* l1_b = (const float*)d_in[13];
  const float* dw_w = (const float*)d_in[14];
  const float* dw_b = (const float*)d_in[15];
  const float* l2_w = (const float*)d_in[16];
  const float* l2_b = (const float*)d_in[17];
  float* out = (float*)d_out;

  // ---- workspace layout, total 253,329,408 B (fits 256 MB) ----
  char* ws = (char*)d_ws;
  short* xn = (short*)ws;                    // [0, 48M): xn -> yb -> xn2
  short* qkv = (short*)(ws + 50331648);      // [48M, 192M): dead after attn
  float* x2 = (float*)(ws + 50331648);       // [48M, 144M): after qkv dead
  short* hbc = (short*)(ws + 150994944);     // 130*256*768*2 = 51,118,080
  short* h2c = (short*)(ws + 202113024);     // 128*256*768*2 = 50,331,648
  short* bt1 = (short*)(ws + 252444672);     // [576][192]
  short* bt2 = bt1 + 110592;                 // [192][192]
  short* bt3 = bt2 + 36864;                  // [768][192]
  short* bt4 = bt3 + 147456;                 // [192][768] ends 253,329,408
  short* yb = xn;   // attn output reuses xn region (xn dead after qkv gemm)
  short* xn2 = xn;  // ln2 output reuses again (yb dead after proj)

  // pre-transpose weights to bf16 [N][K]
  wprep_kernel<<<144, 256, 0, stream>>>(q_w, bt1, 192, 192);
  wprep_kernel<<<288, 256, 0, stream>>>(kv_w, bt1 + 36864, 192, 384);
  wprep_kernel<<<144, 256, 0, stream>>>(proj_w, bt2, 192, 192);
  wprep_kernel<<<576, 256, 0, stream>>>(l1_w, bt3, 192, 768);
  wprep_kernel<<<576, 256, 0, stream>>>(l2_w, bt4, 768, 192);

  ln_kernel<<<32768, 256, 0, stream>>>(x, n1w, n1b, xn);
  gemm_kernel<192, 576, 0><<<dim3(9, 128), 256, 0, stream>>>(
      xn, bt1, q_b, kv_b, nullptr, qkv, 8);
  attn_kernel<<<12288, 64, 0, stream>>>(qkv, rpb, yb);
  gemm_kernel<192, 192, 1><<<dim3(3, 256), 256, 0, stream>>>(
      yb, bt2, proj_b, nullptr, x, x2, 4);
  ln_kernel<<<32768, 256, 0, stream>>>(x2, n2w, n2b, xn2);

  // LeFF in 4 chunks: (batch b, y-half yh), 129 rows w/ 1-row conv halo
  for (int c = 0; c < 4; ++c) {
    int b = c >> 1, yh = c & 1;
    int ystart = yh ? 127 : 0;   // first y row computed by l1 (129 rows)
    int s0 = yh ? 0 : 1;         // hbc slot of ystart
    long tok0 = (long)b * 65536 + (long)ystart * 256;      // l1 input rows
    long ooff = ((long)b * 65536 + (long)yh * 32768) * 192;  // output offset
    gemm_kernel<192, 768, 2><<<dim3(12, 258), 256, 0, stream>>>(
        xn2 + tok0 * 192, bt3, l1_b, nullptr, nullptr,
        hbc + (long)s0 * 196608, 1);
    dwconv_kernel<<<12288, 256, 0, stream>>>(hbc, dw_w, dw_b, h2c, yh);
    gemm_kernel<768, 192, 1><<<dim3(3, 256), 256, 0, stream>>>(
        h2c, bt4, l2_b, nullptr, x2 + ooff / 1, out + ooff, 1);
  }
}